// Round 9
// baseline (499.450 us; speedup 1.0000x reference)
//
#include <hip/hip_runtime.h>

#define TT 2048
#define BB 8
#define DD 1024
#define NN 64
#define C64 64            // timesteps per chunk (= wavefront size)
#define NC2 (TT / C64)    // 32 chunks

typedef __attribute__((ext_vector_type(8))) short bfrag;    // 8 bf16 (4 VGPRs)
typedef __attribute__((ext_vector_type(4))) float f32x4;    // MFMA C/D
typedef __attribute__((ext_vector_type(8))) unsigned short ushort8;

__device__ __forceinline__ float rcp_(float x) { return __builtin_amdgcn_rcpf(x); }
__device__ __forceinline__ float exp2_(float x) {
#if __has_builtin(__builtin_amdgcn_exp2f)
    return __builtin_amdgcn_exp2f(x);
#else
    return exp2f(x);
#endif
}
__device__ __forceinline__ float sigmoidf_(float x) {
    return rcp_(1.0f + __expf(-x));
}
__device__ __forceinline__ float bcastlane(float x, int l) {
    return __int_as_float(__builtin_amdgcn_readlane(__float_as_int(x), l));
}

// DPP multiply-combine with identity=1.0 for masked/invalid lanes.
template <int CTRL, int RM>
__device__ __forceinline__ float dpp_mul1(float x) {
    int v = __builtin_amdgcn_update_dpp(
        0x3f800000, __float_as_int(x), CTRL, RM, 0xF, false);
    return x * __int_as_float(v);
}
// 64-lane inclusive prefix product (canonical GCN scan, ~6 VALU ops)
__device__ __forceinline__ float prefix_mul64(float x) {
    x = dpp_mul1<0x111, 0xF>(x);   // row_shr:1
    x = dpp_mul1<0x112, 0xF>(x);   // row_shr:2
    x = dpp_mul1<0x114, 0xF>(x);   // row_shr:4
    x = dpp_mul1<0x118, 0xF>(x);   // row_shr:8
    x = dpp_mul1<0x142, 0xA>(x);   // row_bcast15 -> rows 1,3
    x = dpp_mul1<0x143, 0xC>(x);   // row_bcast31 -> rows 2,3
    return x;
}

// f32 -> bf16 round-to-nearest-even
__device__ __forceinline__ unsigned short cvt_bf16(float f) {
    unsigned int u = __float_as_uint(f);
    return (unsigned short)((u + 0x7FFF + ((u >> 16) & 1)) >> 16);
}

// async global->LDS, 16 B/lane (LDS dest is wave-uniform base + lane*16)
__device__ __forceinline__ void gll16(const float* g, float* l) {
    __builtin_amdgcn_global_load_lds(
        (const __attribute__((address_space(1))) void*)g,
        (__attribute__((address_space(3))) void*)l, 16, 0, 0);
}

// ---------------------------------------------------------------------------
// Phase 0: W f32 -> bf16, tiled layout Wb[((mat*32+kt)*64+row)*32+col]
// ---------------------------------------------------------------------------
__global__ __launch_bounds__(256) void wcvt_kernel(
    const float* __restrict__ W0, const float* __restrict__ W1,
    const float* __restrict__ W2, const float* __restrict__ W3,
    unsigned short* __restrict__ Wb)
{
    const int i = blockIdx.x * 256 + threadIdx.x;   // 0..32767
    const int o = i * 8;
    const int col = o & 31;            // 0,8,16,24
    const int row = (o >> 5) & 63;
    const int kt  = (o >> 11) & 31;
    const int mat = o >> 16;
    const float* __restrict__ W = (mat == 0) ? W0 : (mat == 1) ? W1
                                 : (mat == 2) ? W2 : W3;
    const float* src = &W[(size_t)row * DD + kt * 32 + col];
    const float4 a = *(const float4*)src;
    const float4 b = *(const float4*)(src + 4);
    ushort8 r;
    r[0] = cvt_bf16(a.x); r[1] = cvt_bf16(a.y);
    r[2] = cvt_bf16(a.z); r[3] = cvt_bf16(a.w);
    r[4] = cvt_bf16(b.x); r[5] = cvt_bf16(b.y);
    r[6] = cvt_bf16(b.z); r[7] = cvt_bf16(b.w);
    *(ushort8*)&Wb[o] = r;
}

// ---------------------------------------------------------------------------
// Phase 1: fused projections (unchanged, known good).
// ---------------------------------------------------------------------------
__global__ __launch_bounds__(256) void proj_fused_kernel(
    const float* __restrict__ x, const unsigned short* __restrict__ Wb,
    const float* __restrict__ b_alpha,
    float* __restrict__ O0, float* __restrict__ O1,
    float* __restrict__ O2, float* __restrict__ O3)
{
    const int m0   = blockIdx.x * 64;
    const int tid  = threadIdx.x;
    const int lane = tid & 63;
    const int wave = tid >> 6;        // 0..3 (also: mat staged by this wave)
    const int ln   = lane & 15;
    const int q8   = (lane >> 4) * 8;

    __shared__ unsigned short As[64][40];
    __shared__ unsigned short Bs[4][64][40];

    f32x4 acc[4][4] = {};             // [mat][nt]

    const int arow = tid >> 2;        // 0..63
    const int aseg = (tid & 3) * 8;   // 0,8,16,24

    float4 pa[2];                     // 8 floats of x
    ushort8 pw[4];                    // 32 bf16 of W (one row of wave's mat)
    {
        const float* ap = &x[(size_t)(m0 + arow) * DD + aseg];
        pa[0] = *(const float4*)ap;
        pa[1] = *(const float4*)(ap + 4);
        const ushort8* wp = (const ushort8*)&Wb[((size_t)(wave * 32 + 0) * 64 + lane) * 32];
        #pragma unroll
        for (int j = 0; j < 4; j++) pw[j] = wp[j];
    }

    for (int k0 = 0; k0 < DD; k0 += 32) {
        __syncthreads();
        {
            unsigned short t8[8];
            const float* pf = (const float*)pa;
            #pragma unroll
            for (int j = 0; j < 8; j++) t8[j] = cvt_bf16(pf[j]);
            *(ushort8*)&As[arow][aseg] = *(ushort8*)&t8[0];
            #pragma unroll
            for (int j = 0; j < 4; j++)
                *(ushort8*)&Bs[wave][lane][8 * j] = pw[j];
        }
        if (k0 + 32 < DD) {
            const int kt = (k0 >> 5) + 1;
            const float* ap = &x[(size_t)(m0 + arow) * DD + k0 + 32 + aseg];
            pa[0] = *(const float4*)ap;
            pa[1] = *(const float4*)(ap + 4);
            const ushort8* wp = (const ushort8*)&Wb[((size_t)(wave * 32 + kt) * 64 + lane) * 32];
            #pragma unroll
            for (int j = 0; j < 4; j++) pw[j] = wp[j];
        }
        __syncthreads();

        const bfrag af = *(const bfrag*)&As[wave * 16 + ln][q8];
        #pragma unroll
        for (int mat = 0; mat < 4; mat++) {
            bfrag bf[4];
            #pragma unroll
            for (int nt = 0; nt < 4; nt++)
                bf[nt] = *(const bfrag*)&Bs[mat][nt * 16 + ln][q8];
            #pragma unroll
            for (int nt = 0; nt < 4; nt++)
                acc[mat][nt] = __builtin_amdgcn_mfma_f32_16x16x32_bf16(
                    af, bf[nt], acc[mat][nt], 0, 0, 0);
        }
    }

    #pragma unroll
    for (int mat = 0; mat < 4; mat++) {
        float* __restrict__ C = (mat == 0) ? O0 : (mat == 1) ? O1
                               : (mat == 2) ? O2 : O3;
        #pragma unroll
        for (int nt = 0; nt < 4; nt++) {
            const int col = nt * 16 + ln;
            const float ba = (mat == 3) ? b_alpha[col] : 0.0f;
            #pragma unroll
            for (int r = 0; r < 4; r++) {
                const int row = m0 + wave * 16 + (lane >> 4) * 4 + r;
                float v = acc[mat][nt][r];
                if (mat == 3) v = sigmoidf_(v + ba);
                C[(size_t)row * NN + col] = v;
            }
        }
    }
}

// ---------------------------------------------------------------------------
// Phase 1.5: per-(b,chunk) Gram matrices, TRANSPOSED + XOR-swizzled
// (unchanged, known good).
// ---------------------------------------------------------------------------
__global__ __launch_bounds__(256) void gram_kernel(
    const float* __restrict__ k_all, const float* __restrict__ q_all,
    float* __restrict__ gkq)
{
    const int c  = blockIdx.x;
    const int b  = blockIdx.y;
    const int t0 = c * C64;
    const int tid = threadIdx.x;

    __shared__ __align__(16) float Ks[64][68];   // +4 pad: bank spread
    __shared__ __align__(16) float Qs[64][68];

    {
        const int r = tid >> 2, sg = (tid & 3) * 16;
        const float* kp = &k_all[(size_t)(t0 + r) * (BB * NN) + b * NN + sg];
        const float* qp = &q_all[(size_t)(t0 + r) * (BB * NN) + b * NN + sg];
        #pragma unroll
        for (int j = 0; j < 4; ++j) {
            *(float4*)&Ks[r][sg + 4 * j] = *(const float4*)(kp + 4 * j);
            *(float4*)&Qs[r][sg + 4 * j] = *(const float4*)(qp + 4 * j);
        }
    }
    __syncthreads();

    const int ti = tid >> 4, tj = tid & 15;
    float g[4][4] = {}, kq[4][4] = {};
    #pragma unroll
    for (int c4 = 0; c4 < 16; ++c4) {
        float4 ka[4], kb[4], qb[4];
        #pragma unroll
        for (int r = 0; r < 4; ++r) {
            ka[r] = *(const float4*)&Ks[4 * ti + r][c4 * 4];
            kb[r] = *(const float4*)&Ks[4 * tj + r][c4 * 4];
            qb[r] = *(const float4*)&Qs[4 * tj + r][c4 * 4];
        }
        #pragma unroll
        for (int r = 0; r < 4; ++r)
            #pragma unroll
            for (int q = 0; q < 4; ++q) {
                g[r][q]  = fmaf(ka[r].x, kb[q].x, g[r][q]);
                g[r][q]  = fmaf(ka[r].y, kb[q].y, g[r][q]);
                g[r][q]  = fmaf(ka[r].z, kb[q].z, g[r][q]);
                g[r][q]  = fmaf(ka[r].w, kb[q].w, g[r][q]);
                kq[r][q] = fmaf(ka[r].x, qb[q].x, kq[r][q]);
                kq[r][q] = fmaf(ka[r].y, qb[q].y, kq[r][q]);
                kq[r][q] = fmaf(ka[r].z, qb[q].z, kq[r][q]);
                kq[r][q] = fmaf(ka[r].w, qb[q].w, kq[r][q]);
            }
    }

    float* base = gkq + (size_t)(b * NC2 + c) * 64 * 128;
    #pragma unroll
    for (int r = 0; r < 4; ++r) {
        #pragma unroll
        for (int q = 0; q < 4; ++q) {
            const int t   = 4 * tj + q;
            const int pos = ((ti ^ (t & 15)) << 2) + r;
            base[t * 128 + pos]      = g[r][q];
            base[t * 128 + 64 + pos] = kq[r][q];
        }
    }
}

// ---------------------------------------------------------------------------
// Phase 2: scan -- FOUR chains (rows) interleaved per wave. The 4 chains'
// per-step serial latencies overlap (independent recurrences in straight-line
// code), amortizing the ~180-cycle per-step stall 4x. Math per row identical
// to round 8's z-chain (passing): z_r += e1_r*u_{r,s}*G[s]*sigma; chain
// readlane -> exp2 -> add -> rcp (+2 muls, 2 fma off-chain per row).
// grid (BB, 16) x 64 thr: 128 single-wave blocks, rows rg*4..rg*4+3.
// ---------------------------------------------------------------------------
__global__ __launch_bounds__(64, 1) void scan_kernel(
    const float* __restrict__ gkq,
    const float* __restrict__ k_all, const float* __restrict__ q_all,
    const float* __restrict__ a_all, const float* __restrict__ v_all,
    const float* __restrict__ S0,
    const float* __restrict__ d_g, const float* __restrict__ b_g,
    float* __restrict__ out, float* __restrict__ S_final)
{
    const int b    = blockIdx.x;
    const int rg   = blockIdx.y;      // 0..15
    const int r0   = rg * 4;
    const int lane = threadIdx.x;     // 0..63 (single wave)
    const int gr    = lane & 15;      // granule within row
    const int s_loc = lane >> 4;      // row within a 4-row K/Q stage call

    __shared__ __align__(16) float gT[2][64 * 128];   // [G^T|KQ^T] swz, 64 KB
    __shared__ __align__(16) float Kl[2][64 * 64];    // K rows swizzled, 32 KB
    __shared__ __align__(16) float Ql[2][64 * 64];    // Q rows swizzled, 32 KB
    __shared__ __align__(16) float sbuf[4][64];       // S broadcast per row

    const float L2E = 1.4426950408889634f;
    const float4 dg4 = *(const float4*)&d_g[r0];
    const float4 bg4 = *(const float4*)&b_g[r0];
    float ndg2[4], nbg2[4], Sr[4];
    #pragma unroll
    for (int r = 0; r < 4; ++r) {
        ndg2[r] = -((const float*)&dg4)[r] * L2E;
        nbg2[r] = -((const float*)&bg4)[r] * L2E;
        Sr[r]   = S0[((size_t)b * NN + r0 + r) * NN + lane];
    }

    const float* gkq_b = gkq + (size_t)b * NC2 * 64 * 128;

    auto stage = [&](int c, int db) {
        const float* src = gkq_b + (size_t)c * 64 * 128;
        #pragma unroll
        for (int j = 0; j < 32; ++j) {
            const int off = (2 * j) * 128;
            gll16(src + off + lane * 4, &gT[db][off]);
        }
        #pragma unroll
        for (int j = 0; j < 16; ++j) {
            const int rr = 4 * j;
            const int s  = rr + s_loc;
            const int gg = gr ^ (s & 15);
            const size_t goff = ((size_t)(c * C64 + s) * BB + b) * NN + gg * 4;
            gll16(k_all + goff, &Kl[db][rr * 64]);
            gll16(q_all + goff, &Ql[db][rr * 64]);
        }
    };

    float4 a_nx, v_nx;
    auto aw_load = [&](int c) {
        const size_t goff = ((size_t)(c * C64 + lane) * BB + b) * NN + r0;
        a_nx = *(const float4*)&a_all[goff];
        v_nx = *(const float4*)&v_all[goff];
    };

    stage(0, 0);
    aw_load(0);

    for (int c = 0; c < NC2; ++c) {
        const int db = c & 1;
        float ac[4], wc[4];
        #pragma unroll
        for (int r = 0; r < 4; ++r) {
            ac[r] = ((const float*)&a_nx)[r];
            wc[r] = (1.0f - ac[r]) * ((const float*)&v_nx)[r];
        }
        __syncthreads();                       // chunk c staged; buf db^1 free
        if (c + 1 < NC2) { aw_load(c + 1); stage(c + 1, db ^ 1); }

        // ---- per-row prefix products + coefficients (lane = step) ----
        float P[4], u[4], e1[4];
        #pragma unroll
        for (int r = 0; r < 4; ++r) {
            P[r]  = prefix_mul64(ac[r]);
            const float Pm = P[r] / ac[r];     // exclusive prefix (lane0 = 1)
            u[r]  = wc[r] * rcp_(P[r]);
            e1[r] = ndg2[r] * Pm;
        }

        // ---- h_t^r = S_r.k_t, hq_t^r = S_r.q_t (lane = t), parallel ----
        #pragma unroll
        for (int r = 0; r < 4; ++r) sbuf[r][lane] = Sr[r];
        const float* Kb = &Kl[db][0];
        const float* Qb = &Ql[db][0];
        f32x4 hk[4] = {}, hqv[4] = {};
        #pragma unroll
        for (int g4 = 0; g4 < 16; ++g4) {
            const int idx = lane * 64 + ((g4 ^ gr) << 2);
            const f32x4 kv = *(const f32x4*)&Kb[idx];
            const f32x4 qv = *(const f32x4*)&Qb[idx];
            #pragma unroll
            for (int r = 0; r < 4; ++r) {
                const f32x4 sv = *(const f32x4*)&sbuf[r][g4 << 2];
                hk[r][0] = fmaf(kv[0], sv[0], hk[r][0]);
                hk[r][1] = fmaf(kv[1], sv[1], hk[r][1]);
                hk[r][2] = fmaf(kv[2], sv[2], hk[r][2]);
                hk[r][3] = fmaf(kv[3], sv[3], hk[r][3]);
                hqv[r][0] = fmaf(qv[0], sv[0], hqv[r][0]);
                hqv[r][1] = fmaf(qv[1], sv[1], hqv[r][1]);
                hqv[r][2] = fmaf(qv[2], sv[2], hqv[r][2]);
                hqv[r][3] = fmaf(qv[3], sv[3], hqv[r][3]);
            }
        }
        float hq[4], z[4], Bacc[4], Bl[4], chl[4];
        #pragma unroll
        for (int r = 0; r < 4; ++r) {
            const float h = (hk[r][0] + hk[r][1]) + (hk[r][2] + hk[r][3]);
            hq[r] = (hqv[r][0] + hqv[r][1]) + (hqv[r][2] + hqv[r][3]);
            z[r]  = fmaf(e1[r], h, nbg2[r]);   // z = e0 (A = 0)
            Bacc[r] = 0.f; Bl[r] = 0.f; chl[r] = 0.f;
        }

        // ---- serial chains, 4 rows interleaved; ping-pong G/KQ prefetch ----
        const float* gt = &gT[db][0];
        const int rowbase = lane * 128;
        f32x4 ga0, ga1, qa0, qa1, gb0, gb1, qb0, qb1;

#define LOADBLK(G0, G1, Q0, Q1, blk) do {                                   \
        const int j0_ = ((2 * (blk)) ^ gr) << 2;                            \
        const int j1_ = ((2 * (blk) + 1) ^ gr) << 2;                        \
        G0 = *(const f32x4*)&gt[rowbase + j0_];                             \
        G1 = *(const f32x4*)&gt[rowbase + j1_];                             \
        Q0 = *(const f32x4*)&gt[rowbase + 64 + j0_];                        \
        Q1 = *(const f32x4*)&gt[rowbase + 64 + j1_];                        \
    } while (0)

#define STEP1(ss, gv, qv) do {                                              \
        float zs_[4], sg_[4], ch_[4];                                       \
        _Pragma("unroll")                                                   \
        for (int r_ = 0; r_ < 4; ++r_) zs_[r_] = bcastlane(z[r_], (ss));    \
        _Pragma("unroll")                                                   \
        for (int r_ = 0; r_ < 4; ++r_)                                      \
            sg_[r_] = rcp_(1.0f + exp2_(zs_[r_]));                          \
        _Pragma("unroll")                                                   \
        for (int r_ = 0; r_ < 4; ++r_)                                      \
            ch_[r_] = sg_[r_] * bcastlane(u[r_], (ss));                     \
        _Pragma("unroll")                                                   \
        for (int r_ = 0; r_ < 4; ++r_) {                                    \
            z[r_]    = fmaf((gv), ch_[r_] * e1[r_], z[r_]);                 \
            Bacc[r_] = fmaf((qv), ch_[r_], Bacc[r_]);                       \
            Bl[r_]   = (lane == (ss)) ? Bacc[r_] : Bl[r_];                  \
            chl[r_]  = (lane == (ss)) ? ch_[r_]  : chl[r_];                 \
        }                                                                   \
    } while (0)

#define STEP8(blk, G0, G1, Q0, Q1)                                          \
        STEP1(8*(blk)+0, G0[0], Q0[0]); STEP1(8*(blk)+1, G0[1], Q0[1]);     \
        STEP1(8*(blk)+2, G0[2], Q0[2]); STEP1(8*(blk)+3, G0[3], Q0[3]);     \
        STEP1(8*(blk)+4, G1[0], Q1[0]); STEP1(8*(blk)+5, G1[1], Q1[1]);     \
        STEP1(8*(blk)+6, G1[2], Q1[2]); STEP1(8*(blk)+7, G1[3], Q1[3]);

        LOADBLK(ga0, ga1, qa0, qa1, 0);
        LOADBLK(gb0, gb1, qb0, qb1, 1);
        STEP8(0, ga0, ga1, qa0, qa1); LOADBLK(ga0, ga1, qa0, qa1, 2);
        STEP8(1, gb0, gb1, qb0, qb1); LOADBLK(gb0, gb1, qb0, qb1, 3);
        STEP8(2, ga0, ga1, qa0, qa1); LOADBLK(ga0, ga1, qa0, qa1, 4);
        STEP8(3, gb0, gb1, qb0, qb1); LOADBLK(gb0, gb1, qb0, qb1, 5);
        STEP8(4, ga0, ga1, qa0, qa1); LOADBLK(ga0, ga1, qa0, qa1, 6);
        STEP8(5, gb0, gb1, qb0, qb1); LOADBLK(gb0, gb1, qb0, qb1, 7);
        STEP8(6, ga0, ga1, qa0, qa1);
        STEP8(7, gb0, gb1, qb0, qb1);

#undef LOADBLK
#undef STEP1
#undef STEP8

        // ---- Sa post-pass (parallel): Sa_r = sum_s ch_{r,s} * K[s][lane] ----
        float Sa[4] = {0.f, 0.f, 0.f, 0.f};
        #pragma unroll
        for (int s = 0; s < 64; ++s) {
            const float kv = Kb[s * 64 +
                ((((lane >> 2) << 2) ^ ((s & 15) << 2))) + (lane & 3)];
            #pragma unroll
            for (int r = 0; r < 4; ++r)
                Sa[r] = fmaf(bcastlane(chl[r], s), kv, Sa[r]);
        }

        // ---- epilogue: outputs (float4 per lane) + state update ----
        float4 y4;
        #pragma unroll
        for (int r = 0; r < 4; ++r) {
            const float o = P[r] * (hq[r] + Bl[r]);
            ((float*)&y4)[r] = o * o * rcp_(1.0f + exp2_(-o * L2E));
            Sr[r] = bcastlane(P[r], 63) * (Sr[r] + Sa[r]);
        }
        *(float4*)&out[((size_t)(c * C64 + lane) * BB + b) * NN + r0] = y4;
    }

    #pragma unroll
    for (int r = 0; r < 4; ++r)
        S_final[((size_t)b * NN + r0 + r) * NN + lane] = Sr[r];
}

// ---------------------------------------------------------------------------
extern "C" void kernel_launch(void* const* d_in, const int* in_sizes, int n_in,
                              void* d_out, int out_size, void* d_ws, size_t ws_size,
                              hipStream_t stream) {
    const float* x       = (const float*)d_in[0];
    const float* S0      = (const float*)d_in[1];
    const float* W_k     = (const float*)d_in[2];
    const float* W_v     = (const float*)d_in[3];
    const float* W_q     = (const float*)d_in[4];
    const float* W_alpha = (const float*)d_in[5];
    const float* b_alpha = (const float*)d_in[6];
    const float* d_g     = (const float*)d_in[7];
    const float* b_g     = (const float*)d_in[8];
    float* out = (float*)d_out;

    const size_t arr = (size_t)TT * BB * NN;          // 1M floats
    float* ws    = (float*)d_ws;
    float* k_all = ws;
    float* v_all = ws + arr;
    float* q_all = ws + 2 * arr;
    float* a_all = ws + 3 * arr;
    float* gkq   = ws + 4 * arr;                      // 2M floats
    unsigned short* Wb = (unsigned short*)(ws + 6 * arr);  // 256K bf16

    wcvt_kernel<<<dim3(128), 256, 0, stream>>>(W_k, W_v, W_q, W_alpha, Wb);

    proj_fused_kernel<<<dim3(TT * BB / 64), 256, 0, stream>>>(
        x, Wb, b_alpha, k_all, v_all, q_all, a_all);

    gram_kernel<<<dim3(NC2, BB), 256, 0, stream>>>(k_all, q_all, gkq);

    scan_kernel<<<dim3(BB, 16), 64, 0, stream>>>(
        gkq, k_all, q_all, a_all, v_all, S0, d_g, b_g, out, out + arr);
}

// Round 10
// 295.100 us; speedup vs baseline: 1.6925x; 1.6925x over previous
//
#include <hip/hip_runtime.h>

#define TT 2048
#define BB 8
#define DD 1024
#define NN 64
#define C64 64            // timesteps per chunk (= wavefront size)
#define NC2 (TT / C64)    // 32 chunks

typedef __attribute__((ext_vector_type(8))) short bfrag;    // 8 bf16 (4 VGPRs)
typedef __attribute__((ext_vector_type(4))) float f32x4;    // MFMA C/D
typedef __attribute__((ext_vector_type(8))) unsigned short ushort8;

__device__ __forceinline__ float rcp_(float x) { return __builtin_amdgcn_rcpf(x); }
__device__ __forceinline__ float exp2_(float x) {
#if __has_builtin(__builtin_amdgcn_exp2f)
    return __builtin_amdgcn_exp2f(x);
#else
    return exp2f(x);
#endif
}
__device__ __forceinline__ float sigmoidf_(float x) {
    return rcp_(1.0f + __expf(-x));
}
__device__ __forceinline__ float bcastlane(float x, int l) {
    return __int_as_float(__builtin_amdgcn_readlane(__float_as_int(x), l));
}

// DPP multiply-combine with identity=1.0 for masked/invalid lanes.
template <int CTRL, int RM>
__device__ __forceinline__ float dpp_mul1(float x) {
    int v = __builtin_amdgcn_update_dpp(
        0x3f800000, __float_as_int(x), CTRL, RM, 0xF, false);
    return x * __int_as_float(v);
}
// 64-lane inclusive prefix product (canonical GCN scan, ~6 VALU ops)
__device__ __forceinline__ float prefix_mul64(float x) {
    x = dpp_mul1<0x111, 0xF>(x);   // row_shr:1
    x = dpp_mul1<0x112, 0xF>(x);   // row_shr:2
    x = dpp_mul1<0x114, 0xF>(x);   // row_shr:4
    x = dpp_mul1<0x118, 0xF>(x);   // row_shr:8
    x = dpp_mul1<0x142, 0xA>(x);   // row_bcast15 -> rows 1,3
    x = dpp_mul1<0x143, 0xC>(x);   // row_bcast31 -> rows 2,3
    return x;
}

// f32 -> bf16 round-to-nearest-even
__device__ __forceinline__ unsigned short cvt_bf16(float f) {
    unsigned int u = __float_as_uint(f);
    return (unsigned short)((u + 0x7FFF + ((u >> 16) & 1)) >> 16);
}

// async global->LDS, 16 B/lane (LDS dest is wave-uniform base + lane*16)
__device__ __forceinline__ void gll16(const float* g, float* l) {
    __builtin_amdgcn_global_load_lds(
        (const __attribute__((address_space(1))) void*)g,
        (__attribute__((address_space(3))) void*)l, 16, 0, 0);
}

// ---------------------------------------------------------------------------
// Phase 0: W f32 -> bf16, tiled layout Wb[((mat*32+kt)*64+row)*32+col]
// ---------------------------------------------------------------------------
__global__ __launch_bounds__(256) void wcvt_kernel(
    const float* __restrict__ W0, const float* __restrict__ W1,
    const float* __restrict__ W2, const float* __restrict__ W3,
    unsigned short* __restrict__ Wb)
{
    const int i = blockIdx.x * 256 + threadIdx.x;   // 0..32767
    const int o = i * 8;
    const int col = o & 31;            // 0,8,16,24
    const int row = (o >> 5) & 63;
    const int kt  = (o >> 11) & 31;
    const int mat = o >> 16;
    const float* __restrict__ W = (mat == 0) ? W0 : (mat == 1) ? W1
                                 : (mat == 2) ? W2 : W3;
    const float* src = &W[(size_t)row * DD + kt * 32 + col];
    const float4 a = *(const float4*)src;
    const float4 b = *(const float4*)(src + 4);
    ushort8 r;
    r[0] = cvt_bf16(a.x); r[1] = cvt_bf16(a.y);
    r[2] = cvt_bf16(a.z); r[3] = cvt_bf16(a.w);
    r[4] = cvt_bf16(b.x); r[5] = cvt_bf16(b.y);
    r[6] = cvt_bf16(b.z); r[7] = cvt_bf16(b.w);
    *(ushort8*)&Wb[o] = r;
}

// ---------------------------------------------------------------------------
// Phase 1: fused projections, DOUBLE-BUFFERED LDS, ONE barrier per k-step
// (was 2). Per iter: write buf[cur] (disjoint from buf[cur^1] being MFMA-read
// by laggard waves), barrier, MFMA from buf[cur]; prefetch kt+1 into regs.
// grid 256 blocks x 256 thr.
// ---------------------------------------------------------------------------
__global__ __launch_bounds__(256) void proj_fused_kernel(
    const float* __restrict__ x, const unsigned short* __restrict__ Wb,
    const float* __restrict__ b_alpha,
    float* __restrict__ O0, float* __restrict__ O1,
    float* __restrict__ O2, float* __restrict__ O3)
{
    const int m0   = blockIdx.x * 64;
    const int tid  = threadIdx.x;
    const int lane = tid & 63;
    const int wave = tid >> 6;        // 0..3 (also: mat staged by this wave)
    const int ln   = lane & 15;
    const int q8   = (lane >> 4) * 8;

    __shared__ unsigned short As[2][64][40];
    __shared__ unsigned short Bs[2][4][64][40];

    f32x4 acc[4][4] = {};             // [mat][nt]

    const int arow = tid >> 2;        // 0..63
    const int aseg = (tid & 3) * 8;   // 0,8,16,24

    float4 pa[2];                     // 8 floats of x
    ushort8 pw[4];                    // 32 bf16 of W (one row of wave's mat)
    {
        const float* ap = &x[(size_t)(m0 + arow) * DD + aseg];
        pa[0] = *(const float4*)ap;
        pa[1] = *(const float4*)(ap + 4);
        const ushort8* wp = (const ushort8*)&Wb[((size_t)(wave * 32 + 0) * 64 + lane) * 32];
        #pragma unroll
        for (int j = 0; j < 4; j++) pw[j] = wp[j];
    }

    for (int kt = 0; kt < 32; ++kt) {
        const int cur = kt & 1;
        {
            unsigned short t8[8];
            const float* pf = (const float*)pa;
            #pragma unroll
            for (int j = 0; j < 8; j++) t8[j] = cvt_bf16(pf[j]);
            *(ushort8*)&As[cur][arow][aseg] = *(ushort8*)&t8[0];
            #pragma unroll
            for (int j = 0; j < 4; j++)
                *(ushort8*)&Bs[cur][wave][lane][8 * j] = pw[j];
        }
        if (kt + 1 < 32) {
            const float* ap = &x[(size_t)(m0 + arow) * DD + (kt + 1) * 32 + aseg];
            pa[0] = *(const float4*)ap;
            pa[1] = *(const float4*)(ap + 4);
            const ushort8* wp = (const ushort8*)&Wb[((size_t)(wave * 32 + kt + 1) * 64 + lane) * 32];
            #pragma unroll
            for (int j = 0; j < 4; j++) pw[j] = wp[j];
        }
        __syncthreads();

        const bfrag af = *(const bfrag*)&As[cur][wave * 16 + ln][q8];
        #pragma unroll
        for (int mat = 0; mat < 4; mat++) {
            bfrag bf[4];
            #pragma unroll
            for (int nt = 0; nt < 4; nt++)
                bf[nt] = *(const bfrag*)&Bs[cur][mat][nt * 16 + ln][q8];
            #pragma unroll
            for (int nt = 0; nt < 4; nt++)
                acc[mat][nt] = __builtin_amdgcn_mfma_f32_16x16x32_bf16(
                    af, bf[nt], acc[mat][nt], 0, 0, 0);
        }
    }

    #pragma unroll
    for (int mat = 0; mat < 4; mat++) {
        float* __restrict__ C = (mat == 0) ? O0 : (mat == 1) ? O1
                               : (mat == 2) ? O2 : O3;
        #pragma unroll
        for (int nt = 0; nt < 4; nt++) {
            const int col = nt * 16 + ln;
            const float ba = (mat == 3) ? b_alpha[col] : 0.0f;
            #pragma unroll
            for (int r = 0; r < 4; r++) {
                const int row = m0 + wave * 16 + (lane >> 4) * 4 + r;
                float v = acc[mat][nt][r];
                if (mat == 3) v = sigmoidf_(v + ba);
                C[(size_t)row * NN + col] = v;
            }
        }
    }
}

// ---------------------------------------------------------------------------
// Phase 1.5: per-(b,chunk) Gram matrices, TRANSPOSED + XOR-swizzled, now
// TRIANGULAR-MASKED: G entry (s,t) kept only for s<t (strict), KQ for s<=t.
// This makes lane t's z/Bacc in the scan stop changing after step t, so the
// scan's per-step latch cndmasks disappear.
// ---------------------------------------------------------------------------
__global__ __launch_bounds__(256) void gram_kernel(
    const float* __restrict__ k_all, const float* __restrict__ q_all,
    float* __restrict__ gkq)
{
    const int c  = blockIdx.x;
    const int b  = blockIdx.y;
    const int t0 = c * C64;
    const int tid = threadIdx.x;

    __shared__ __align__(16) float Ks[64][68];   // +4 pad: bank spread
    __shared__ __align__(16) float Qs[64][68];

    {
        const int r = tid >> 2, sg = (tid & 3) * 16;
        const float* kp = &k_all[(size_t)(t0 + r) * (BB * NN) + b * NN + sg];
        const float* qp = &q_all[(size_t)(t0 + r) * (BB * NN) + b * NN + sg];
        #pragma unroll
        for (int j = 0; j < 4; ++j) {
            *(float4*)&Ks[r][sg + 4 * j] = *(const float4*)(kp + 4 * j);
            *(float4*)&Qs[r][sg + 4 * j] = *(const float4*)(qp + 4 * j);
        }
    }
    __syncthreads();

    const int ti = tid >> 4, tj = tid & 15;
    float g[4][4] = {}, kq[4][4] = {};
    #pragma unroll
    for (int c4 = 0; c4 < 16; ++c4) {
        float4 ka[4], kb[4], qb[4];
        #pragma unroll
        for (int r = 0; r < 4; ++r) {
            ka[r] = *(const float4*)&Ks[4 * ti + r][c4 * 4];
            kb[r] = *(const float4*)&Ks[4 * tj + r][c4 * 4];
            qb[r] = *(const float4*)&Qs[4 * tj + r][c4 * 4];
        }
        #pragma unroll
        for (int r = 0; r < 4; ++r)
            #pragma unroll
            for (int q = 0; q < 4; ++q) {
                g[r][q]  = fmaf(ka[r].x, kb[q].x, g[r][q]);
                g[r][q]  = fmaf(ka[r].y, kb[q].y, g[r][q]);
                g[r][q]  = fmaf(ka[r].z, kb[q].z, g[r][q]);
                g[r][q]  = fmaf(ka[r].w, kb[q].w, g[r][q]);
                kq[r][q] = fmaf(ka[r].x, qb[q].x, kq[r][q]);
                kq[r][q] = fmaf(ka[r].y, qb[q].y, kq[r][q]);
                kq[r][q] = fmaf(ka[r].z, qb[q].z, kq[r][q]);
                kq[r][q] = fmaf(ka[r].w, qb[q].w, kq[r][q]);
            }
    }

    float* base = gkq + (size_t)(b * NC2 + c) * 64 * 128;
    #pragma unroll
    for (int r = 0; r < 4; ++r) {
        const int s = 4 * ti + r;
        #pragma unroll
        for (int q = 0; q < 4; ++q) {
            const int t   = 4 * tj + q;
            const int pos = ((ti ^ (t & 15)) << 2) + r;
            base[t * 128 + pos]      = (s <  t) ? g[r][q]  : 0.0f;
            base[t * 128 + 64 + pos] = (s <= t) ? kq[r][q] : 0.0f;
        }
    }
}

// ---------------------------------------------------------------------------
// Phase 2: scan (round-8 structure, proven). Triangular-masked G/KQ means
// lane t's z and Bacc are final after step t: the per-step latch cndmasks are
// gone; sigma/ch recomputed once post-loop from the (preserved) z. Serial
// chain: readlane(z,s) -> exp2 -> add -> rcp -> fma. grid (BB,32) x 128 thr.
// ---------------------------------------------------------------------------
__global__ __launch_bounds__(128, 1) void scan_kernel(
    const float* __restrict__ gkq,
    const float* __restrict__ k_all, const float* __restrict__ q_all,
    const float* __restrict__ a_all, const float* __restrict__ v_all,
    const float* __restrict__ S0,
    const float* __restrict__ d_g, const float* __restrict__ b_g,
    float* __restrict__ out, float* __restrict__ S_final)
{
    const int b    = blockIdx.x;
    const int rg   = blockIdx.y;      // 0..31
    const int tid  = threadIdx.x;
    const int lane = tid & 63;
    const int wave = tid >> 6;        // 0..1
    const int row  = rg * 2 + wave;

    __shared__ __align__(16) float gT[2][64 * 128];   // [G^T|KQ^T] swz, 64 KB
    __shared__ __align__(16) float Kl[2][64 * 64];    // K rows swizzled, 32 KB
    __shared__ __align__(16) float Ql[2][64 * 64];    // Q rows swizzled, 32 KB
    __shared__ __align__(16) float sbuf[2][64];       // per-wave S broadcast

    float S = S0[((size_t)b * NN + row) * NN + lane];
    const float L2E  = 1.4426950408889634f;
    const float ndg2 = -d_g[row] * L2E;
    const float nbg2 = -b_g[row] * L2E;

    const float* gkq_b = gkq + (size_t)b * NC2 * 64 * 128;

    const int s_loc = lane >> 4;      // row within a 4-row K/Q stage call
    const int gr    = lane & 15;      // granule within row

    auto stage = [&](int c, int db) {
        const float* src = gkq_b + (size_t)c * 64 * 128;
        #pragma unroll
        for (int j = 0; j < 16; ++j) {
            const int off = (wave * 32 + 2 * j) * 128;
            gll16(src + off + lane * 4, &gT[db][off]);
        }
        #pragma unroll
        for (int j = 0; j < 8; ++j) {
            const int r0 = wave * 32 + 4 * j;
            const int s  = r0 + s_loc;
            const int gg = gr ^ (s & 15);
            const size_t goff = ((size_t)(c * C64 + s) * BB + b) * NN + gg * 4;
            gll16(k_all + goff, &Kl[db][r0 * 64]);
            gll16(q_all + goff, &Ql[db][r0 * 64]);
        }
    };

    float a_nx, v_nx;
    auto aw_load = [&](int c) {
        const size_t goff = ((size_t)(c * C64 + lane) * BB + b) * NN + row;
        a_nx = a_all[goff];
        v_nx = v_all[goff];
    };

    stage(0, 0);
    aw_load(0);

    for (int c = 0; c < NC2; ++c) {
        const int db = c & 1;
        const float ac = a_nx;
        const float wc = (1.0f - a_nx) * v_nx;
        __syncthreads();                       // chunk c staged; buf db^1 free
        if (c + 1 < NC2) { aw_load(c + 1); stage(c + 1, db ^ 1); }

        // ---- prefix product over alpha via DPP (lane = step) ----
        const float P  = prefix_mul64(ac);
        const float Pm = P / ac;               // exclusive prefix (lane0 = 1)
        const float u  = wc * rcp_(P);

        // ---- h_t = S.k_t, hq_t = S.q_t (lane = t), parallel ----
        sbuf[wave][lane] = S;
        const float* Kb = &Kl[db][0];
        const float* Qb = &Ql[db][0];
        float4 ha = {0.f, 0.f, 0.f, 0.f};
        float4 hb = {0.f, 0.f, 0.f, 0.f};
        #pragma unroll
        for (int g4 = 0; g4 < 16; ++g4) {
            const int idx = lane * 64 + ((g4 ^ gr) << 2);
            float4 kv = *(const float4*)&Kb[idx];
            float4 qv = *(const float4*)&Qb[idx];
            float4 sv = *(const float4*)&sbuf[wave][g4 << 2];
            ha.x = fmaf(kv.x, sv.x, ha.x); ha.y = fmaf(kv.y, sv.y, ha.y);
            ha.z = fmaf(kv.z, sv.z, ha.z); ha.w = fmaf(kv.w, sv.w, ha.w);
            hb.x = fmaf(qv.x, sv.x, hb.x); hb.y = fmaf(qv.y, sv.y, hb.y);
            hb.z = fmaf(qv.z, sv.z, hb.z); hb.w = fmaf(qv.w, sv.w, hb.w);
        }
        const float h  = (ha.x + ha.y) + (ha.z + ha.w);
        const float hq = (hb.x + hb.y) + (hb.z + hb.w);
        const float e1 = ndg2 * Pm;            // z_t = e1_t*A_t + e0_t
        const float e0 = fmaf(e1, h, nbg2);

        // ---- serial chain on z: 8 blocks x 8 steps, ping-pong prefetch ----
        const float* gt = &gT[db][0];
        const int rowbase = lane * 128;

        float z = e0;                          // A = 0
        float Bacc = 0.f;

        f32x4 g2a0, g2a1, q2a0, q2a1, g2b0, g2b1, q2b0, q2b1;

#define LOADBLK(G0, G1, Q0, Q1, blk) do {                                   \
        const int j0_ = ((2 * (blk)) ^ gr) << 2;                            \
        const int j1_ = ((2 * (blk) + 1) ^ gr) << 2;                        \
        const f32x4 rg0_ = *(const f32x4*)&gt[rowbase + j0_];               \
        const f32x4 rg1_ = *(const f32x4*)&gt[rowbase + j1_];               \
        const f32x4 rq0_ = *(const f32x4*)&gt[rowbase + 64 + j0_];          \
        const f32x4 rq1_ = *(const f32x4*)&gt[rowbase + 64 + j1_];          \
        const float u0_ = bcastlane(u, 8*(blk)+0);                          \
        const float u1_ = bcastlane(u, 8*(blk)+1);                          \
        const float u2_ = bcastlane(u, 8*(blk)+2);                          \
        const float u3_ = bcastlane(u, 8*(blk)+3);                          \
        const float u4_ = bcastlane(u, 8*(blk)+4);                          \
        const float u5_ = bcastlane(u, 8*(blk)+5);                          \
        const float u6_ = bcastlane(u, 8*(blk)+6);                          \
        const float u7_ = bcastlane(u, 8*(blk)+7);                          \
        Q0[0] = rq0_[0]*u0_; Q0[1] = rq0_[1]*u1_;                           \
        Q0[2] = rq0_[2]*u2_; Q0[3] = rq0_[3]*u3_;                           \
        Q1[0] = rq1_[0]*u4_; Q1[1] = rq1_[1]*u5_;                           \
        Q1[2] = rq1_[2]*u6_; Q1[3] = rq1_[3]*u7_;                           \
        G0[0] = rg0_[0]*u0_*e1; G0[1] = rg0_[1]*u1_*e1;                     \
        G0[2] = rg0_[2]*u2_*e1; G0[3] = rg0_[3]*u3_*e1;                     \
        G1[0] = rg1_[0]*u4_*e1; G1[1] = rg1_[1]*u5_*e1;                     \
        G1[2] = rg1_[2]*u6_*e1; G1[3] = rg1_[3]*u7_*e1;                     \
    } while (0)

#define STEP1(ss, gv, qv) do {                                              \
        const float zs_ = bcastlane(z, (ss));                               \
        const float sg_ = rcp_(1.0f + exp2_(zs_));                          \
        z    = fmaf((gv), sg_, z);                                          \
        Bacc = fmaf((qv), sg_, Bacc);                                       \
    } while (0)

#define STEP8(blk, G0, G1, Q0, Q1)                                          \
        STEP1(8*(blk)+0, G0[0], Q0[0]); STEP1(8*(blk)+1, G0[1], Q0[1]);     \
        STEP1(8*(blk)+2, G0[2], Q0[2]); STEP1(8*(blk)+3, G0[3], Q0[3]);     \
        STEP1(8*(blk)+4, G1[0], Q1[0]); STEP1(8*(blk)+5, G1[1], Q1[1]);     \
        STEP1(8*(blk)+6, G1[2], Q1[2]); STEP1(8*(blk)+7, G1[3], Q1[3]);

        LOADBLK(g2a0, g2a1, q2a0, q2a1, 0);
        LOADBLK(g2b0, g2b1, q2b0, q2b1, 1);
        STEP8(0, g2a0, g2a1, q2a0, q2a1); LOADBLK(g2a0, g2a1, q2a0, q2a1, 2);
        STEP8(1, g2b0, g2b1, q2b0, q2b1); LOADBLK(g2b0, g2b1, q2b0, q2b1, 3);
        STEP8(2, g2a0, g2a1, q2a0, q2a1); LOADBLK(g2a0, g2a1, q2a0, q2a1, 4);
        STEP8(3, g2b0, g2b1, q2b0, q2b1); LOADBLK(g2b0, g2b1, q2b0, q2b1, 5);
        STEP8(4, g2a0, g2a1, q2a0, q2a1); LOADBLK(g2a0, g2a1, q2a0, q2a1, 6);
        STEP8(5, g2b0, g2b1, q2b0, q2b1); LOADBLK(g2b0, g2b1, q2b0, q2b1, 7);
        STEP8(6, g2a0, g2a1, q2a0, q2a1);
        STEP8(7, g2b0, g2b1, q2b0, q2b1);

#undef LOADBLK
#undef STEP1
#undef STEP8

        // ---- post-loop: sigma/ch recomputed from final z (lane = t) ----
        const float sgf = rcp_(1.0f + exp2_(z));     // sigma_t
        const float chl = u * sgf;                   // ch_t

        // ---- Sa post-pass (parallel, 4-way ILP): Sa = sum_s ch_s*K[s][lane]
        float Sa0 = 0.f, Sa1 = 0.f, Sa2 = 0.f, Sa3 = 0.f;
        #pragma unroll
        for (int s = 0; s < 64; s += 4) {
            const float c0 = bcastlane(chl, s);
            const float c1 = bcastlane(chl, s + 1);
            const float c2 = bcastlane(chl, s + 2);
            const float c3 = bcastlane(chl, s + 3);
            const int sw = ((lane >> 2) << 2);
            Sa0 = fmaf(c0, Kb[(s)     * 64 + ((sw ^ (((s)     & 15) << 2))) + (lane & 3)], Sa0);
            Sa1 = fmaf(c1, Kb[(s + 1) * 64 + ((sw ^ (((s + 1) & 15) << 2))) + (lane & 3)], Sa1);
            Sa2 = fmaf(c2, Kb[(s + 2) * 64 + ((sw ^ (((s + 2) & 15) << 2))) + (lane & 3)], Sa2);
            Sa3 = fmaf(c3, Kb[(s + 3) * 64 + ((sw ^ (((s + 3) & 15) << 2))) + (lane & 3)], Sa3);
        }
        const float Sa = (Sa0 + Sa1) + (Sa2 + Sa3);

        // ---- epilogue: outputs + state update ----
        const float o = P * (hq + Bacc);
        const float y = o * o * rcp_(1.0f + exp2_(-o * L2E));
        out[((size_t)(c * C64 + lane) * BB + b) * NN + row] = y;
        const float Pl = bcastlane(P, 63);
        S = Pl * (S + Sa);
    }

    S_final[((size_t)b * NN + row) * NN + lane] = S;
}

// ---------------------------------------------------------------------------
extern "C" void kernel_launch(void* const* d_in, const int* in_sizes, int n_in,
                              void* d_out, int out_size, void* d_ws, size_t ws_size,
                              hipStream_t stream) {
    const float* x       = (const float*)d_in[0];
    const float* S0      = (const float*)d_in[1];
    const float* W_k     = (const float*)d_in[2];
    const float* W_v     = (const float*)d_in[3];
    const float* W_q     = (const float*)d_in[4];
    const float* W_alpha = (const float*)d_in[5];
    const float* b_alpha = (const float*)d_in[6];
    const float* d_g     = (const float*)d_in[7];
    const float* b_g     = (const float*)d_in[8];
    float* out = (float*)d_out;

    const size_t arr = (size_t)TT * BB * NN;          // 1M floats
    float* ws    = (float*)d_ws;
    float* k_all = ws;
    float* v_all = ws + arr;
    float* q_all = ws + 2 * arr;
    float* a_all = ws + 3 * arr;
    float* gkq   = ws + 4 * arr;                      // 2M floats
    unsigned short* Wb = (unsigned short*)(ws + 6 * arr);  // 256K bf16

    wcvt_kernel<<<dim3(128), 256, 0, stream>>>(W_k, W_v, W_q, W_alpha, Wb);

    proj_fused_kernel<<<dim3(TT * BB / 64), 256, 0, stream>>>(
        x, Wb, b_alpha, k_all, v_all, q_all, a_all);

    gram_kernel<<<dim3(NC2, BB), 256, 0, stream>>>(k_all, q_all, gkq);

    scan_kernel<<<dim3(BB, 32), 128, 0, stream>>>(
        gkq, k_all, q_all, a_all, v_all, S0, d_g, b_g, out, out + arr);
}